// Round 3
// baseline (2342.295 us; speedup 1.0000x reference)
//
#include <hip/hip_runtime.h>

#define NS 500000
#define NG 20000
#define NN 600000
#define NF 8
#define EPS_ 1e-5f

#define NBIN NS
#define NBLK ((NBIN + 255) / 256)   // 1954
#define STRIPS 32
#define NODES_PER_STRIP (NN / STRIPS)  // 18750

// ---------------- K1: w = mean_f filters; also copy filters -> out ----------------
__global__ __launch_bounds__(256) void k_w_copy(const float* __restrict__ filters,
                                                float* __restrict__ w,
                                                float* __restrict__ out_f) {
  int i = blockIdx.x * 256 + threadIdx.x;
  const int n4 = NS / 4;  // 125000
  if (i >= n4) return;
  const float4* f4 = (const float4*)filters;
  float4* o4 = (float4*)out_f;
  float sx = 0.f, sy = 0.f, sz = 0.f, sw = 0.f;
#pragma unroll
  for (int f = 0; f < NF; f++) {
    float4 v = f4[(size_t)f * n4 + i];
    o4[(size_t)f * n4 + i] = v;
    sx += v.x; sy += v.y; sz += v.z; sw += v.w;
  }
  float4 r;
  r.x = sx * 0.125f; r.y = sy * 0.125f; r.z = sz * 0.125f; r.w = sw * 0.125f;
  ((float4*)w)[i] = r;
}

// ---------------- counting sort of nodes by snp id ----------------
__global__ __launch_bounds__(256) void k_hist_s(const int* __restrict__ snp_ids,
                                                int* __restrict__ cnt) {
  int j = blockIdx.x * 256 + threadIdx.x;
  if (j < NN) atomicAdd(&cnt[snp_ids[j]], 1);
}

// per-256-bin block sums
__global__ __launch_bounds__(256) void k_blocksum(const int* __restrict__ cnt,
                                                  int* __restrict__ bsum) {
  int i = blockIdx.x * 256 + threadIdx.x;
  int v = (i < NBIN) ? cnt[i] : 0;
#pragma unroll
  for (int d = 32; d > 0; d >>= 1) v += __shfl_xor(v, d, 64);
  __shared__ int r[4];
  int wv = threadIdx.x >> 6;
  if ((threadIdx.x & 63) == 0) r[wv] = v;
  __syncthreads();
  if (threadIdx.x == 0) bsum[blockIdx.x] = r[0] + r[1] + r[2] + r[3];
}

// single-block scan of the 1954 block sums -> exclusive bases
__global__ __launch_bounds__(1024) void k_scanb(const int* __restrict__ bsum,
                                                int* __restrict__ ebase) {
  __shared__ int part[1024];
  int t = threadIdx.x;
  int base = t * 2;
  int s = 0;
#pragma unroll
  for (int i = 0; i < 2; i++) {
    int g = base + i;
    if (g < NBLK) s += bsum[g];
  }
  part[t] = s;
  __syncthreads();
  for (int d = 1; d < 1024; d <<= 1) {
    int v = 0;
    if (t >= d) v = part[t - d];
    __syncthreads();
    part[t] += v;
    __syncthreads();
  }
  int run = part[t] - s;
#pragma unroll
  for (int i = 0; i < 2; i++) {
    int g = base + i;
    if (g < NBLK) {
      ebase[g] = run;
      run += bsum[g];
    }
  }
}

// per-bin exclusive offsets -> cursor
__global__ __launch_bounds__(256) void k_offsets(const int* __restrict__ cnt,
                                                 const int* __restrict__ ebase,
                                                 int* __restrict__ cursor) {
  __shared__ int sc[256];
  int t = threadIdx.x;
  int i = blockIdx.x * 256 + t;
  int c = (i < NBIN) ? cnt[i] : 0;
  sc[t] = c;
  __syncthreads();
  for (int d = 1; d < 256; d <<= 1) {
    int v = 0;
    if (t >= d) v = sc[t - d];
    __syncthreads();
    sc[t] += v;
    __syncthreads();
  }
  if (i < NBIN) cursor[i] = ebase[blockIdx.x] + sc[t] - c;
}

// scatter nodes into sid-sorted order; fold w gather here
__global__ __launch_bounds__(256) void k_sortnodes_s(const int* __restrict__ snp_ids,
                                                     const int* __restrict__ node_gene,
                                                     const float* __restrict__ w,
                                                     int* __restrict__ cursor,
                                                     int* __restrict__ sorted_sid,
                                                     int* __restrict__ sorted_gene,
                                                     float* __restrict__ wv) {
  int j = blockIdx.x * 256 + threadIdx.x;
  if (j >= NN) return;
  int sid = snp_ids[j];
  int pos = atomicAdd(&cursor[sid], 1);
  sorted_sid[pos] = sid;
  sorted_gene[pos] = node_gene[j];
  wv[pos] = w[sid];
}

// ---------------- gather + scatter-add: geneT[g][b] += snp[b][sid]*w[sid] ----------------
// block = (strip of nodes, group of 4 batches). Sorted sids -> near-sequential gathers.
__global__ __launch_bounds__(256) void k_scatter_add(const float* __restrict__ snp,
                                                     const int* __restrict__ sorted_sid,
                                                     const int* __restrict__ sorted_gene,
                                                     const float* __restrict__ wv,
                                                     float* __restrict__ geneT) {
  int strip = blockIdx.x >> 4;           // 0..31
  int b0 = (blockIdx.x & 15) * 4;        // 0,4,...,60
  int j0 = strip * NODES_PER_STRIP;
  int j1 = j0 + NODES_PER_STRIP;
  const float* r0 = snp + (size_t)(b0 + 0) * NS;
  const float* r1 = snp + (size_t)(b0 + 1) * NS;
  const float* r2 = snp + (size_t)(b0 + 2) * NS;
  const float* r3 = snp + (size_t)(b0 + 3) * NS;
  for (int j = j0 + threadIdx.x; j < j1; j += 256) {
    int sid = sorted_sid[j];
    int g = sorted_gene[j];
    float v = wv[j];
    float* dst = geneT + (size_t)g * 64 + b0;
    unsafeAtomicAdd(dst + 0, r0[sid] * v);
    unsafeAtomicAdd(dst + 1, r1[sid] * v);
    unsafeAtomicAdd(dst + 2, r2[sid] * v);
    unsafeAtomicAdd(dst + 3, r3[sid] * v);
  }
}

// ---------------- streamed split-K GEMM ----------------
// partial[slice][n][b] = sum over k-slice of XT[k][b]*Wm[k][n]
// block 256: lane owns 4 consecutive cols (float4 of Wm row), wave owns 16 batches.
template <int NCOLS>
__global__ __launch_bounds__(256) void k_gemm_stream(const float* __restrict__ XT,
                                                     const float* __restrict__ Wm,
                                                     float* __restrict__ partial,
                                                     int KTOT, int kPerSlice) {
  int tid = threadIdx.x;
  int lane = tid & 63;
  int wv = tid >> 6;
  int c0 = blockIdx.x * 256 + lane * 4;
  int b0 = wv * 16;
  int kBeg = blockIdx.y * kPerSlice;
  int kEnd = KTOT < kBeg + kPerSlice ? KTOT : kBeg + kPerSlice;

  float acc[4][16];
#pragma unroll
  for (int i = 0; i < 4; i++)
#pragma unroll
    for (int j = 0; j < 16; j++) acc[i][j] = 0.f;

#pragma unroll 2
  for (int k = kBeg; k < kEnd; k++) {
    float4 wr = *(const float4*)(Wm + (size_t)k * NCOLS + c0);
    const float4* gp = (const float4*)(XT + (size_t)k * 64 + b0);
    float4 g0 = gp[0], g1 = gp[1], g2 = gp[2], g3 = gp[3];
    float gg[16];
    gg[0] = g0.x; gg[1] = g0.y; gg[2] = g0.z; gg[3] = g0.w;
    gg[4] = g1.x; gg[5] = g1.y; gg[6] = g1.z; gg[7] = g1.w;
    gg[8] = g2.x; gg[9] = g2.y; gg[10] = g2.z; gg[11] = g2.w;
    gg[12] = g3.x; gg[13] = g3.y; gg[14] = g3.z; gg[15] = g3.w;
#pragma unroll
    for (int j = 0; j < 16; j++) {
      acc[0][j] = fmaf(wr.x, gg[j], acc[0][j]);
      acc[1][j] = fmaf(wr.y, gg[j], acc[1][j]);
      acc[2][j] = fmaf(wr.z, gg[j], acc[2][j]);
      acc[3][j] = fmaf(wr.w, gg[j], acc[3][j]);
    }
  }

  float* pb = partial + (size_t)blockIdx.y * NCOLS * 64;
#pragma unroll
  for (int i = 0; i < 4; i++) {
    float4* dst = (float4*)(pb + (size_t)(c0 + i) * 64 + b0);
#pragma unroll
    for (int q = 0; q < 4; q++) {
      float4 v;
      v.x = acc[i][q * 4 + 0]; v.y = acc[i][q * 4 + 1];
      v.z = acc[i][q * 4 + 2]; v.w = acc[i][q * 4 + 3];
      dst[q] = v;
    }
  }
}

// ---------------- fused split-K reduce + BatchNorm + ReLU ----------------
__global__ __launch_bounds__(256) void k_reduce_bn(const float* __restrict__ partial,
                                                   int S, int ncols,
                                                   const float* __restrict__ gamma,
                                                   const float* __restrict__ beta,
                                                   float* __restrict__ outT) {
  int n = blockIdx.x * 4 + (threadIdx.x >> 6);
  int b = threadIdx.x & 63;
  size_t stride = (size_t)ncols * 64;
  const float* p = partial + (size_t)n * 64 + b;
  float x0 = 0.f, x1 = 0.f, x2 = 0.f, x3 = 0.f;
  int s = 0;
  for (; s + 4 <= S; s += 4) {
    x0 += p[(size_t)(s + 0) * stride];
    x1 += p[(size_t)(s + 1) * stride];
    x2 += p[(size_t)(s + 2) * stride];
    x3 += p[(size_t)(s + 3) * stride];
  }
  for (; s < S; s++) x0 += p[(size_t)s * stride];
  float x = (x0 + x1) + (x2 + x3);
  float s1 = x, s2 = x * x;
#pragma unroll
  for (int d = 32; d > 0; d >>= 1) {
    s1 += __shfl_xor(s1, d, 64);
    s2 += __shfl_xor(s2, d, 64);
  }
  float m = s1 * (1.f / 64.f);
  float v = s2 * (1.f / 64.f) - m * m;
  float y = gamma[n] * (x - m) * rsqrtf(v + EPS_) + beta[n];
  outT[(size_t)n * 64 + b] = fmaxf(y, 0.f);
}

// ---------------- head: preds[b] = sum_k h2T[k][b]*W3[k] + b3 ----------------
__global__ __launch_bounds__(64) void k_head(const float* __restrict__ h2T,
                                             const float* __restrict__ W3,
                                             const float* __restrict__ b3,
                                             float* __restrict__ out) {
  int b = threadIdx.x;
  float acc = 0.f;
  for (int k = 0; k < 256; k++) acc = fmaf(h2T[(size_t)k * 64 + b], W3[k], acc);
  out[b] = acc + b3[0];
}

// ---------------- workspace layout (4 B elements) ----------------
static constexpr int S1 = 128;
static constexpr int S2 = 128;
static constexpr size_t N_W = NS;                       // 500,000
static constexpr size_t N_GENET = (size_t)NG * 64;      // 1,280,000
static constexpr size_t N_P1 = (size_t)S1 * 1024 * 64;  // 8,388,608
static constexpr size_t N_P2 = (size_t)S2 * 256 * 64;   // 2,097,152

extern "C" void kernel_launch(void* const* d_in, const int* in_sizes, int n_in,
                              void* d_out, int out_size, void* d_ws, size_t ws_size,
                              hipStream_t stream) {
  const float* snp       = (const float*)d_in[0];
  const int*   snp_ids   = (const int*)d_in[1];
  const int*   node_gene = (const int*)d_in[2];
  const float* filters   = (const float*)d_in[3];
  const float* W1        = (const float*)d_in[4];
  const float* g1        = (const float*)d_in[6];
  const float* beta1     = (const float*)d_in[7];
  const float* W2        = (const float*)d_in[8];
  const float* g2        = (const float*)d_in[10];
  const float* beta2     = (const float*)d_in[11];
  const float* W3        = (const float*)d_in[12];
  const float* b3        = (const float*)d_in[13];
  float* out = (float*)d_out;
  float* ws  = (float*)d_ws;

  float* w      = ws;
  float* geneT  = w + N_W;
  float* h1T    = geneT + N_GENET;
  float* h2T    = h1T + 65536;
  float* p1     = h2T + 16384;
  float* p2     = p1 + N_P1;
  float* wv     = p2 + N_P2;
  int* cnt      = (int*)(wv + NN);
  int* cursor   = cnt + NBIN;
  int* bsum     = cursor + NBIN;
  int* ebase    = bsum + 2048;
  int* ssid     = ebase + 2048;
  int* sgene    = ssid + NN;

  // zero-init: histogram counters + gene accumulator
  hipMemsetAsync(cnt, 0, NBIN * sizeof(int), stream);
  hipMemsetAsync(geneT, 0, N_GENET * sizeof(float), stream);

  // w = mean_f filters; copy filters -> out[64..]
  k_w_copy<<<(NS / 4 + 255) / 256, 256, 0, stream>>>(filters, w, out + 64);

  // counting sort of nodes by snp id (two-level scan over 500k bins)
  k_hist_s<<<(NN + 255) / 256, 256, 0, stream>>>(snp_ids, cnt);
  k_blocksum<<<NBLK, 256, 0, stream>>>(cnt, bsum);
  k_scanb<<<1, 1024, 0, stream>>>(bsum, ebase);
  k_offsets<<<NBLK, 256, 0, stream>>>(cnt, ebase, cursor);
  k_sortnodes_s<<<(NN + 255) / 256, 256, 0, stream>>>(snp_ids, node_gene, w, cursor,
                                                      ssid, sgene, wv);

  // gather (near-sequential) + scatter-add into geneT[g][b]
  k_scatter_add<<<STRIPS * 16, 256, 0, stream>>>(snp, ssid, sgene, wv, geneT);

  // MLP layer 1: [64,20000]x[20000,1024]
  int kps1 = (NG + S1 - 1) / S1;  // 157
  k_gemm_stream<1024><<<dim3(4, S1), 256, 0, stream>>>(geneT, W1, p1, NG, kps1);
  k_reduce_bn<<<1024 / 4, 256, 0, stream>>>(p1, S1, 1024, g1, beta1, h1T);

  // MLP layer 2: [64,1024]x[1024,256]
  int kps2 = 1024 / S2;  // 8
  k_gemm_stream<256><<<dim3(1, S2), 256, 0, stream>>>(h1T, W2, p2, 1024, kps2);
  k_reduce_bn<<<256 / 4, 256, 0, stream>>>(p2, S2, 256, g2, beta2, h2T);

  // head
  k_head<<<1, 64, 0, stream>>>(h2T, W3, b3, out);
}

// Round 4
// 679.782 us; speedup vs baseline: 3.4457x; 3.4457x over previous
//
#include <hip/hip_runtime.h>

#define NS 500000
#define NG 20000
#define NN 600000
#define NF 8
#define EPS_ 1e-5f

#define NBIN NS
#define NBLK ((NBIN + 255) / 256)   // 1954

// ---------------- K1: w = mean_f filters; also copy filters -> out ----------------
__global__ __launch_bounds__(256) void k_w_copy(const float* __restrict__ filters,
                                                float* __restrict__ w,
                                                float* __restrict__ out_f) {
  int i = blockIdx.x * 256 + threadIdx.x;
  const int n4 = NS / 4;  // 125000
  if (i >= n4) return;
  const float4* f4 = (const float4*)filters;
  float4* o4 = (float4*)out_f;
  float sx = 0.f, sy = 0.f, sz = 0.f, sw = 0.f;
#pragma unroll
  for (int f = 0; f < NF; f++) {
    float4 v = f4[(size_t)f * n4 + i];
    o4[(size_t)f * n4 + i] = v;
    sx += v.x; sy += v.y; sz += v.z; sw += v.w;
  }
  float4 r;
  r.x = sx * 0.125f; r.y = sy * 0.125f; r.z = sz * 0.125f; r.w = sw * 0.125f;
  ((float4*)w)[i] = r;
}

// ---------------- counting sort of nodes by snp id ----------------
__global__ __launch_bounds__(256) void k_hist_s(const int* __restrict__ snp_ids,
                                                int* __restrict__ cnt) {
  int j = blockIdx.x * 256 + threadIdx.x;
  if (j < NN) atomicAdd(&cnt[snp_ids[j]], 1);
}

__global__ __launch_bounds__(256) void k_blocksum(const int* __restrict__ cnt,
                                                  int* __restrict__ bsum) {
  int i = blockIdx.x * 256 + threadIdx.x;
  int v = (i < NBIN) ? cnt[i] : 0;
#pragma unroll
  for (int d = 32; d > 0; d >>= 1) v += __shfl_xor(v, d, 64);
  __shared__ int r[4];
  int wv = threadIdx.x >> 6;
  if ((threadIdx.x & 63) == 0) r[wv] = v;
  __syncthreads();
  if (threadIdx.x == 0) bsum[blockIdx.x] = r[0] + r[1] + r[2] + r[3];
}

__global__ __launch_bounds__(1024) void k_scanb(const int* __restrict__ bsum,
                                                int* __restrict__ ebase) {
  __shared__ int part[1024];
  int t = threadIdx.x;
  int base = t * 2;
  int s = 0;
#pragma unroll
  for (int i = 0; i < 2; i++) {
    int g = base + i;
    if (g < NBLK) s += bsum[g];
  }
  part[t] = s;
  __syncthreads();
  for (int d = 1; d < 1024; d <<= 1) {
    int v = 0;
    if (t >= d) v = part[t - d];
    __syncthreads();
    part[t] += v;
    __syncthreads();
  }
  int run = part[t] - s;
#pragma unroll
  for (int i = 0; i < 2; i++) {
    int g = base + i;
    if (g < NBLK) {
      ebase[g] = run;
      run += bsum[g];
    }
  }
}

__global__ __launch_bounds__(256) void k_offsets(const int* __restrict__ cnt,
                                                 const int* __restrict__ ebase,
                                                 int* __restrict__ cursor) {
  __shared__ int sc[256];
  int t = threadIdx.x;
  int i = blockIdx.x * 256 + t;
  int c = (i < NBIN) ? cnt[i] : 0;
  sc[t] = c;
  __syncthreads();
  for (int d = 1; d < 256; d <<= 1) {
    int v = 0;
    if (t >= d) v = sc[t - d];
    __syncthreads();
    sc[t] += v;
    __syncthreads();
  }
  if (i < NBIN) cursor[i] = ebase[blockIdx.x] + sc[t] - c;
}

// scatter nodes into sid-sorted order as packed {sid, gene}
__global__ __launch_bounds__(256) void k_sortnodes_s(const int* __restrict__ snp_ids,
                                                     const int* __restrict__ node_gene,
                                                     int* __restrict__ cursor,
                                                     int2* __restrict__ sgpack) {
  int j = blockIdx.x * 256 + threadIdx.x;
  if (j >= NN) return;
  int sid = snp_ids[j];
  int pos = atomicAdd(&cursor[sid], 1);
  sgpack[pos] = make_int2(sid, node_gene[j]);
}

// ---------------- scatter into LDS gene accumulator (full 80 KB variant) ----------------
// block = (batch b, strip of NN/8 sid-sorted nodes); dynamic LDS acc[NG].
__global__ __launch_bounds__(512) void k_scatter_full(const float* __restrict__ snp,
                                                      const int2* __restrict__ sgpack,
                                                      const float* __restrict__ w,
                                                      float* __restrict__ partial) {
  extern __shared__ float acc[];  // NG floats = 80000 B
  int b = blockIdx.x & 63;
  int strip = blockIdx.x >> 6;  // 0..7
  for (int i = threadIdx.x; i < NG; i += 512) acc[i] = 0.f;
  __syncthreads();
  const int NPS = NN / 8;
  int j0 = strip * NPS, j1 = j0 + NPS;
  const float* row = snp + (size_t)b * NS;
  for (int j = j0 + threadIdx.x; j < j1; j += 512) {
    int2 sg = sgpack[j];
    atomicAdd(&acc[sg.y], row[sg.x] * w[sg.x]);
  }
  __syncthreads();
  float* dst = partial + ((size_t)b * 8 + strip) * NG;
  for (int i = threadIdx.x; i < NG; i += 512) dst[i] = acc[i];
}

// ---------------- fallback: 40 KB static LDS, gene-halves ----------------
// block = (b, strip of NN/4 nodes, gene half); predicate on half.
__global__ __launch_bounds__(256) void k_scatter_half(const float* __restrict__ snp,
                                                      const int2* __restrict__ sgpack,
                                                      const float* __restrict__ w,
                                                      float* __restrict__ partial) {
  __shared__ float acc[NG / 2];  // 40 KB
  int b = blockIdx.x & 63;
  int sh = blockIdx.x >> 6;   // 0..7
  int strip = sh >> 1;        // 0..3
  int half = sh & 1;
  for (int i = threadIdx.x; i < NG / 2; i += 256) acc[i] = 0.f;
  __syncthreads();
  int gbase = half * (NG / 2);
  const int NPS = NN / 4;
  int j0 = strip * NPS, j1 = j0 + NPS;
  const float* row = snp + (size_t)b * NS;
  for (int j = j0 + threadIdx.x; j < j1; j += 256) {
    int2 sg = sgpack[j];
    unsigned g = (unsigned)(sg.y - gbase);
    if (g < (unsigned)(NG / 2)) atomicAdd(&acc[g], row[sg.x] * w[sg.x]);
  }
  __syncthreads();
  float* dst = partial + ((size_t)b * 4 + strip) * NG + gbase;
  for (int i = threadIdx.x; i < NG / 2; i += 256) dst[i] = acc[i];
}

// ---------------- reduce strips -> geneT[g][b] via LDS transpose ----------------
__global__ __launch_bounds__(256) void k_reduce_gene(const float* __restrict__ partial,
                                                     int S, float* __restrict__ geneT) {
  __shared__ float tile[64][65];
  int t = threadIdx.x;
  int g0 = blockIdx.x * 64;
  int gi = t & 63, bq = t >> 6;
#pragma unroll
  for (int i = 0; i < 16; i++) {
    int b = i * 4 + bq;
    int g = g0 + gi;
    float a = 0.f;
    if (g < NG)
      for (int s = 0; s < S; s++) a += partial[((size_t)b * S + s) * NG + g];
    tile[b][gi] = a;
  }
  __syncthreads();
  int bb = t & 63, gq = t >> 6;
#pragma unroll
  for (int j = 0; j < 16; j++) {
    int gi2 = j * 4 + gq;
    int g = g0 + gi2;
    if (g < NG) geneT[(size_t)g * 64 + bb] = tile[bb][gi2];
  }
}

// ---------------- streamed split-K GEMM ----------------
template <int NCOLS>
__global__ __launch_bounds__(256) void k_gemm_stream(const float* __restrict__ XT,
                                                     const float* __restrict__ Wm,
                                                     float* __restrict__ partial,
                                                     int KTOT, int kPerSlice) {
  int tid = threadIdx.x;
  int lane = tid & 63;
  int wv = tid >> 6;
  int c0 = blockIdx.x * 256 + lane * 4;
  int b0 = wv * 16;
  int kBeg = blockIdx.y * kPerSlice;
  int kEnd = KTOT < kBeg + kPerSlice ? KTOT : kBeg + kPerSlice;

  float acc[4][16];
#pragma unroll
  for (int i = 0; i < 4; i++)
#pragma unroll
    for (int j = 0; j < 16; j++) acc[i][j] = 0.f;

#pragma unroll 2
  for (int k = kBeg; k < kEnd; k++) {
    float4 wr = *(const float4*)(Wm + (size_t)k * NCOLS + c0);
    const float4* gp = (const float4*)(XT + (size_t)k * 64 + b0);
    float4 g0 = gp[0], g1 = gp[1], g2 = gp[2], g3 = gp[3];
    float gg[16];
    gg[0] = g0.x; gg[1] = g0.y; gg[2] = g0.z; gg[3] = g0.w;
    gg[4] = g1.x; gg[5] = g1.y; gg[6] = g1.z; gg[7] = g1.w;
    gg[8] = g2.x; gg[9] = g2.y; gg[10] = g2.z; gg[11] = g2.w;
    gg[12] = g3.x; gg[13] = g3.y; gg[14] = g3.z; gg[15] = g3.w;
#pragma unroll
    for (int j = 0; j < 16; j++) {
      acc[0][j] = fmaf(wr.x, gg[j], acc[0][j]);
      acc[1][j] = fmaf(wr.y, gg[j], acc[1][j]);
      acc[2][j] = fmaf(wr.z, gg[j], acc[2][j]);
      acc[3][j] = fmaf(wr.w, gg[j], acc[3][j]);
    }
  }

  float* pb = partial + (size_t)blockIdx.y * NCOLS * 64;
#pragma unroll
  for (int i = 0; i < 4; i++) {
    float4* dst = (float4*)(pb + (size_t)(c0 + i) * 64 + b0);
#pragma unroll
    for (int q = 0; q < 4; q++) {
      float4 v;
      v.x = acc[i][q * 4 + 0]; v.y = acc[i][q * 4 + 1];
      v.z = acc[i][q * 4 + 2]; v.w = acc[i][q * 4 + 3];
      dst[q] = v;
    }
  }
}

// ---------------- fused split-K reduce + BatchNorm + ReLU ----------------
__global__ __launch_bounds__(256) void k_reduce_bn(const float* __restrict__ partial,
                                                   int S, int ncols,
                                                   const float* __restrict__ gamma,
                                                   const float* __restrict__ beta,
                                                   float* __restrict__ outT) {
  int n = blockIdx.x * 4 + (threadIdx.x >> 6);
  int b = threadIdx.x & 63;
  size_t stride = (size_t)ncols * 64;
  const float* p = partial + (size_t)n * 64 + b;
  float x0 = 0.f, x1 = 0.f, x2 = 0.f, x3 = 0.f;
  int s = 0;
  for (; s + 4 <= S; s += 4) {
    x0 += p[(size_t)(s + 0) * stride];
    x1 += p[(size_t)(s + 1) * stride];
    x2 += p[(size_t)(s + 2) * stride];
    x3 += p[(size_t)(s + 3) * stride];
  }
  for (; s < S; s++) x0 += p[(size_t)s * stride];
  float x = (x0 + x1) + (x2 + x3);
  float s1 = x, s2 = x * x;
#pragma unroll
  for (int d = 32; d > 0; d >>= 1) {
    s1 += __shfl_xor(s1, d, 64);
    s2 += __shfl_xor(s2, d, 64);
  }
  float m = s1 * (1.f / 64.f);
  float v = s2 * (1.f / 64.f) - m * m;
  float y = gamma[n] * (x - m) * rsqrtf(v + EPS_) + beta[n];
  outT[(size_t)n * 64 + b] = fmaxf(y, 0.f);
}

// ---------------- head ----------------
__global__ __launch_bounds__(64) void k_head(const float* __restrict__ h2T,
                                             const float* __restrict__ W3,
                                             const float* __restrict__ b3,
                                             float* __restrict__ out) {
  int b = threadIdx.x;
  float acc = 0.f;
  for (int k = 0; k < 256; k++) acc = fmaf(h2T[(size_t)k * 64 + b], W3[k], acc);
  out[b] = acc + b3[0];
}

// ---------------- workspace layout (4 B elements) ----------------
static constexpr int S1 = 256;
static constexpr int S2 = 128;
static constexpr size_t N_W = NS;                        // 500,000
static constexpr size_t N_GENET = (size_t)NG * 64;       // 1,280,000
static constexpr size_t N_P1 = (size_t)S1 * 1024 * 64;   // 16,777,216
static constexpr size_t N_P2 = (size_t)S2 * 256 * 64;    // 2,097,152
static constexpr size_t N_PARTG = (size_t)64 * 8 * NG;   // 10,240,000

extern "C" void kernel_launch(void* const* d_in, const int* in_sizes, int n_in,
                              void* d_out, int out_size, void* d_ws, size_t ws_size,
                              hipStream_t stream) {
  const float* snp       = (const float*)d_in[0];
  const int*   snp_ids   = (const int*)d_in[1];
  const int*   node_gene = (const int*)d_in[2];
  const float* filters   = (const float*)d_in[3];
  const float* W1        = (const float*)d_in[4];
  const float* g1        = (const float*)d_in[6];
  const float* beta1     = (const float*)d_in[7];
  const float* W2        = (const float*)d_in[8];
  const float* g2        = (const float*)d_in[10];
  const float* beta2     = (const float*)d_in[11];
  const float* W3        = (const float*)d_in[12];
  const float* b3        = (const float*)d_in[13];
  float* out = (float*)d_out;
  float* ws  = (float*)d_ws;

  float* w      = ws;
  float* geneT  = w + N_W;
  float* h1T    = geneT + N_GENET;
  float* h2T    = h1T + 65536;
  float* p1     = h2T + 16384;
  float* p2     = p1 + N_P1;
  float* partG  = p2 + N_P2;
  int* cnt      = (int*)(partG + N_PARTG);
  int* cursor   = cnt + NBIN;
  int* bsum     = cursor + NBIN;
  int* ebase    = bsum + 2048;
  int2* sgpack  = (int2*)(ebase + 2048);   // 600,000 int2

  // runtime LDS capability check (deterministic per device -> capture-safe)
  int dev = 0;
  hipGetDevice(&dev);
  int maxShm = 0;
  hipDeviceGetAttribute(&maxShm, hipDeviceAttributeMaxSharedMemoryPerBlock, dev);
  bool bigLds = maxShm >= (int)(NG * sizeof(float));
  if (bigLds) {
    hipFuncSetAttribute(reinterpret_cast<const void*>(k_scatter_full),
                        hipFuncAttributeMaxDynamicSharedMemorySize,
                        (int)(NG * sizeof(float)));
  }

  // zero-init histogram counters
  hipMemsetAsync(cnt, 0, NBIN * sizeof(int), stream);

  // w = mean_f filters; copy filters -> out[64..]
  k_w_copy<<<(NS / 4 + 255) / 256, 256, 0, stream>>>(filters, w, out + 64);

  // counting sort of nodes by snp id
  k_hist_s<<<(NN + 255) / 256, 256, 0, stream>>>(snp_ids, cnt);
  k_blocksum<<<NBLK, 256, 0, stream>>>(cnt, bsum);
  k_scanb<<<1, 1024, 0, stream>>>(bsum, ebase);
  k_offsets<<<NBLK, 256, 0, stream>>>(cnt, ebase, cursor);
  k_sortnodes_s<<<(NN + 255) / 256, 256, 0, stream>>>(snp_ids, node_gene, cursor, sgpack);

  // gather + LDS scatter-add -> strip partials -> geneT
  int S;
  if (bigLds) {
    S = 8;
    k_scatter_full<<<64 * 8, 512, NG * sizeof(float), stream>>>(snp, sgpack, w, partG);
  } else {
    S = 4;
    k_scatter_half<<<64 * 8, 256, 0, stream>>>(snp, sgpack, w, partG);
  }
  k_reduce_gene<<<(NG + 63) / 64, 256, 0, stream>>>(partG, S, geneT);

  // MLP layer 1: [64,20000]x[20000,1024]
  int kps1 = (NG + S1 - 1) / S1;  // 79
  k_gemm_stream<1024><<<dim3(4, S1), 256, 0, stream>>>(geneT, W1, p1, NG, kps1);
  k_reduce_bn<<<1024 / 4, 256, 0, stream>>>(p1, S1, 1024, g1, beta1, h1T);

  // MLP layer 2: [64,1024]x[1024,256]
  int kps2 = 1024 / S2;  // 8
  k_gemm_stream<256><<<dim3(1, S2), 256, 0, stream>>>(h1T, W2, p2, 1024, kps2);
  k_reduce_bn<<<256 / 4, 256, 0, stream>>>(p2, S2, 256, g2, beta2, h2T);

  // head
  k_head<<<1, 64, 0, stream>>>(h2T, W3, b3, out);
}

// Round 5
// 509.704 us; speedup vs baseline: 4.5954x; 1.3337x over previous
//
#include <hip/hip_runtime.h>

#define NS 500000
#define NG 20000
#define NN 600000
#define NF 8
#define EPS_ 1e-5f

// ---------------- K1: w = mean_f filters; also copy filters -> out ----------------
__global__ __launch_bounds__(256) void k_w_copy(const float* __restrict__ filters,
                                                float* __restrict__ w,
                                                float* __restrict__ out_f) {
  int i = blockIdx.x * 256 + threadIdx.x;
  const int n4 = NS / 4;  // 125000
  if (i >= n4) return;
  const float4* f4 = (const float4*)filters;
  float4* o4 = (float4*)out_f;
  float sx = 0.f, sy = 0.f, sz = 0.f, sw = 0.f;
#pragma unroll
  for (int f = 0; f < NF; f++) {
    float4 v = f4[(size_t)f * n4 + i];
    o4[(size_t)f * n4 + i] = v;
    sx += v.x; sy += v.y; sz += v.z; sw += v.w;
  }
  float4 r;
  r.x = sx * 0.125f; r.y = sy * 0.125f; r.z = sz * 0.125f; r.w = sw * 0.125f;
  ((float4*)w)[i] = r;
}

// ---------------- gene counting sort ----------------
__global__ __launch_bounds__(256) void k_hist(const int* __restrict__ node_gene,
                                              int* __restrict__ cnt) {
  int j = blockIdx.x * 256 + threadIdx.x;
  if (j < NN) atomicAdd(&cnt[node_gene[j]], 1);
}

__global__ __launch_bounds__(1024) void k_scan(const int* __restrict__ cnt,
                                               int* __restrict__ offs,
                                               int* __restrict__ cursor) {
  __shared__ int part[1024];
  int t = threadIdx.x;
  int base = t * 20;  // 1024*20 = 20480 >= 20000
  int s = 0;
  for (int i = 0; i < 20; i++) {
    int g = base + i;
    if (g < NG) s += cnt[g];
  }
  part[t] = s;
  __syncthreads();
  for (int d = 1; d < 1024; d <<= 1) {
    int v = 0;
    if (t >= d) v = part[t - d];
    __syncthreads();
    part[t] += v;
    __syncthreads();
  }
  int run = part[t] - s;
  for (int i = 0; i < 20; i++) {
    int g = base + i;
    if (g < NG) {
      offs[g] = run;
      cursor[g] = run;
      run += cnt[g];
    }
  }
  if (t == 1023) offs[NG] = part[1023];
}

__global__ __launch_bounds__(256) void k_sortnodes(const int* __restrict__ snp_ids,
                                                   const int* __restrict__ node_gene,
                                                   int* __restrict__ cursor,
                                                   int* __restrict__ sorted_sid) {
  int j = blockIdx.x * 256 + threadIdx.x;
  if (j >= NN) return;
  int g = node_gene[j];
  int pos = atomicAdd(&cursor[g], 1);
  sorted_sid[pos] = snp_ids[j];
}

// ---------------- transpose v2: snpT[s][b] = snp[b][s] * w[s] ----------------
// float4 global loads, conflict-free LDS (2-way only), coalesced 256B wave stores.
__global__ __launch_bounds__(256) void k_transpose(const float* __restrict__ snp,
                                                   const float* __restrict__ w,
                                                   float* __restrict__ snpT) {
  __shared__ float tile[64 * 65];
  int t = threadIdx.x;
  int s0 = blockIdx.x * 64;
  // load phase: f = float4 index along sid, rows b = wq*16 + i*4 + r
  int f = t & 15;
  int r = (t >> 4) & 3;
  int wq = t >> 6;
#pragma unroll
  for (int i = 0; i < 4; i++) {
    int b = wq * 16 + i * 4 + r;
    float4 v = make_float4(0.f, 0.f, 0.f, 0.f);
    if (s0 + 4 * f < NS) v = *(const float4*)(snp + (size_t)b * NS + s0 + 4 * f);
    float* tp = tile + b * 65 + 4 * f;
    tp[0] = v.x; tp[1] = v.y; tp[2] = v.z; tp[3] = v.w;
  }
  // per-lane w (coalesced); broadcast per-sid via shfl in store loop
  int lane = t & 63;
  float wl = (s0 + lane < NS) ? w[s0 + lane] : 0.f;
  __syncthreads();
  // store phase: lane = batch, iterate 16 sids per wave (sq = wave id)
  int sq = t >> 6;
#pragma unroll
  for (int i = 0; i < 16; i++) {
    int sl = sq * 16 + i;
    float x = tile[lane * 65 + sl];
    float wv = __shfl(wl, sl, 64);
    if (s0 + sl < NS) snpT[(size_t)(s0 + sl) * 64 + lane] = x * wv;
  }
}

// ---------------- accum v2: wave per gene, lane = batch, 4-node ILP ----------------
__global__ __launch_bounds__(256) void k_accum_T(const float* __restrict__ snpT,
                                                 const int* __restrict__ offs,
                                                 const int* __restrict__ sorted_sid,
                                                 float* __restrict__ geneT) {
  int wave = (blockIdx.x * 256 + threadIdx.x) >> 6;
  int lane = threadIdx.x & 63;
  if (wave >= NG) return;
  int beg = offs[wave], end = offs[wave + 1];
  float a0 = 0.f, a1 = 0.f, a2 = 0.f, a3 = 0.f;
  int n = beg;
  for (; n + 4 <= end; n += 4) {
    int s0 = sorted_sid[n + 0];
    int s1 = sorted_sid[n + 1];
    int s2 = sorted_sid[n + 2];
    int s3 = sorted_sid[n + 3];
    float v0 = snpT[(size_t)s0 * 64 + lane];
    float v1 = snpT[(size_t)s1 * 64 + lane];
    float v2 = snpT[(size_t)s2 * 64 + lane];
    float v3 = snpT[(size_t)s3 * 64 + lane];
    a0 += v0; a1 += v1; a2 += v2; a3 += v3;
  }
  for (; n < end; n++) a0 += snpT[(size_t)sorted_sid[n] * 64 + lane];
  geneT[(size_t)wave * 64 + lane] = (a0 + a1) + (a2 + a3);
}

// ---------------- split-K GEMM with LDS-staged X ----------------
// K-loop per wave: 1 coalesced float4 W-load + 4 broadcast ds_read_b128 + 64 FMA.
template <int NCOLS, int KPSMAX>
__global__ __launch_bounds__(256) void k_gemm_stream(const float* __restrict__ XT,
                                                     const float* __restrict__ Wm,
                                                     float* __restrict__ partial,
                                                     int KTOT, int kPerSlice) {
  __shared__ float xs[KPSMAX * 64];
  int tid = threadIdx.x;
  int lane = tid & 63;
  int wv = tid >> 6;
  int c0 = blockIdx.x * 256 + lane * 4;
  int b0 = wv * 16;
  int kBeg = blockIdx.y * kPerSlice;
  int kEnd = KTOT < kBeg + kPerSlice ? KTOT : kBeg + kPerSlice;
  int kc = kEnd - kBeg;

  // stage X slice into LDS (coalesced float4)
  {
    const float4* src = (const float4*)(XT + (size_t)kBeg * 64);
    float4* dst = (float4*)xs;
    for (int i = tid; i < kc * 16; i += 256) dst[i] = src[i];
  }
  __syncthreads();

  float acc[4][16];
#pragma unroll
  for (int i = 0; i < 4; i++)
#pragma unroll
    for (int j = 0; j < 16; j++) acc[i][j] = 0.f;

#pragma unroll 2
  for (int kk = 0; kk < kc; kk++) {
    float4 wr = *(const float4*)(Wm + (size_t)(kBeg + kk) * NCOLS + c0);
    const float4* xp = (const float4*)(xs + kk * 64 + b0);
    float4 g0 = xp[0], g1 = xp[1], g2 = xp[2], g3 = xp[3];
    float gg[16];
    gg[0] = g0.x; gg[1] = g0.y; gg[2] = g0.z; gg[3] = g0.w;
    gg[4] = g1.x; gg[5] = g1.y; gg[6] = g1.z; gg[7] = g1.w;
    gg[8] = g2.x; gg[9] = g2.y; gg[10] = g2.z; gg[11] = g2.w;
    gg[12] = g3.x; gg[13] = g3.y; gg[14] = g3.z; gg[15] = g3.w;
#pragma unroll
    for (int j = 0; j < 16; j++) {
      acc[0][j] = fmaf(wr.x, gg[j], acc[0][j]);
      acc[1][j] = fmaf(wr.y, gg[j], acc[1][j]);
      acc[2][j] = fmaf(wr.z, gg[j], acc[2][j]);
      acc[3][j] = fmaf(wr.w, gg[j], acc[3][j]);
    }
  }

  float* pb = partial + (size_t)blockIdx.y * NCOLS * 64;
#pragma unroll
  for (int i = 0; i < 4; i++) {
    float4* dst = (float4*)(pb + (size_t)(c0 + i) * 64 + b0);
#pragma unroll
    for (int q = 0; q < 4; q++) {
      float4 v;
      v.x = acc[i][q * 4 + 0]; v.y = acc[i][q * 4 + 1];
      v.z = acc[i][q * 4 + 2]; v.w = acc[i][q * 4 + 3];
      dst[q] = v;
    }
  }
}

// ---------------- fused split-K reduce + BatchNorm + ReLU ----------------
__global__ __launch_bounds__(256) void k_reduce_bn(const float* __restrict__ partial,
                                                   int S, int ncols,
                                                   const float* __restrict__ gamma,
                                                   const float* __restrict__ beta,
                                                   float* __restrict__ outT) {
  int n = blockIdx.x * 4 + (threadIdx.x >> 6);
  int b = threadIdx.x & 63;
  size_t stride = (size_t)ncols * 64;
  const float* p = partial + (size_t)n * 64 + b;
  float x0 = 0.f, x1 = 0.f, x2 = 0.f, x3 = 0.f;
  int s = 0;
  for (; s + 4 <= S; s += 4) {
    x0 += p[(size_t)(s + 0) * stride];
    x1 += p[(size_t)(s + 1) * stride];
    x2 += p[(size_t)(s + 2) * stride];
    x3 += p[(size_t)(s + 3) * stride];
  }
  for (; s < S; s++) x0 += p[(size_t)s * stride];
  float x = (x0 + x1) + (x2 + x3);
  float s1 = x, s2 = x * x;
#pragma unroll
  for (int d = 32; d > 0; d >>= 1) {
    s1 += __shfl_xor(s1, d, 64);
    s2 += __shfl_xor(s2, d, 64);
  }
  float m = s1 * (1.f / 64.f);
  float v = s2 * (1.f / 64.f) - m * m;
  float y = gamma[n] * (x - m) * rsqrtf(v + EPS_) + beta[n];
  outT[(size_t)n * 64 + b] = fmaxf(y, 0.f);
}

// ---------------- head ----------------
__global__ __launch_bounds__(64) void k_head(const float* __restrict__ h2T,
                                             const float* __restrict__ W3,
                                             const float* __restrict__ b3,
                                             float* __restrict__ out) {
  int b = threadIdx.x;
  float acc = 0.f;
  for (int k = 0; k < 256; k++) acc = fmaf(h2T[(size_t)k * 64 + b], W3[k], acc);
  out[b] = acc + b3[0];
}

// ---------------- workspace layout (4 B elements) ----------------
static constexpr int S1 = 128;
static constexpr int S2 = 128;
static constexpr size_t N_W = NS;                        // 500,000
static constexpr size_t N_SNPT = (size_t)NS * 64;        // 32,000,000
static constexpr size_t N_GENET = (size_t)NG * 64;       // 1,280,000
static constexpr size_t N_P1 = (size_t)S1 * 1024 * 64;   // 8,388,608 (aliases snpT)
static constexpr size_t N_P2 = (size_t)S2 * 256 * 64;    // 2,097,152 (aliases snpT)

extern "C" void kernel_launch(void* const* d_in, const int* in_sizes, int n_in,
                              void* d_out, int out_size, void* d_ws, size_t ws_size,
                              hipStream_t stream) {
  const float* snp       = (const float*)d_in[0];
  const int*   snp_ids   = (const int*)d_in[1];
  const int*   node_gene = (const int*)d_in[2];
  const float* filters   = (const float*)d_in[3];
  const float* W1        = (const float*)d_in[4];
  const float* g1        = (const float*)d_in[6];
  const float* beta1     = (const float*)d_in[7];
  const float* W2        = (const float*)d_in[8];
  const float* g2        = (const float*)d_in[10];
  const float* beta2     = (const float*)d_in[11];
  const float* W3        = (const float*)d_in[12];
  const float* b3        = (const float*)d_in[13];
  float* out = (float*)d_out;
  float* ws  = (float*)d_ws;

  float* w      = ws;                 // 500,000
  float* snpT   = ws + N_W;           // 32,000,000 (dead after accum)
  float* p1     = snpT;               // alias
  float* p2     = p1 + N_P1;          // alias
  float* geneT  = snpT + N_SNPT;      // 1,280,000
  float* h1T    = geneT + N_GENET;    // 65,536
  float* h2T    = h1T + 65536;        // 16,384
  int* cnt      = (int*)(h2T + 16384);
  int* offs     = cnt + NG;           // NG+1 used, pad to 20064
  int* cursor   = offs + 20064;
  int* sorted   = cursor + NG;        // 600,000

  // zero histogram counters
  hipMemsetAsync(cnt, 0, NG * sizeof(int), stream);

  // w = mean_f filters; copy filters -> out[64..]
  k_w_copy<<<(NS / 4 + 255) / 256, 256, 0, stream>>>(filters, w, out + 64);

  // counting sort of nodes by gene
  k_hist<<<(NN + 255) / 256, 256, 0, stream>>>(node_gene, cnt);
  k_scan<<<1, 1024, 0, stream>>>(cnt, offs, cursor);
  k_sortnodes<<<(NN + 255) / 256, 256, 0, stream>>>(snp_ids, node_gene, cursor, sorted);

  // transpose (w folded) + gene accumulation
  k_transpose<<<(NS + 63) / 64, 256, 0, stream>>>(snp, w, snpT);
  k_accum_T<<<(NG * 64) / 256, 256, 0, stream>>>(snpT, offs, sorted, geneT);

  // MLP layer 1: [64,20000] x [20000,1024]
  int kps1 = (NG + S1 - 1) / S1;  // 157
  k_gemm_stream<1024, 157><<<dim3(4, S1), 256, 0, stream>>>(geneT, W1, p1, NG, kps1);
  k_reduce_bn<<<1024 / 4, 256, 0, stream>>>(p1, S1, 1024, g1, beta1, h1T);

  // MLP layer 2: [64,1024] x [1024,256]
  int kps2 = 1024 / S2;  // 8
  k_gemm_stream<256, 8><<<dim3(1, S2), 256, 0, stream>>>(h1T, W2, p2, 1024, kps2);
  k_reduce_bn<<<256 / 4, 256, 0, stream>>>(p2, S2, 256, g2, beta2, h2T);

  // head
  k_head<<<1, 64, 0, stream>>>(h2T, W3, b3, out);
}